// Round 15
// baseline (354.780 us; speedup 1.0000x reference)
//
#include <hip/hip_runtime.h>
#include <hip/hip_bf16.h>

#define N_NODES 50000
#define F_IN    1024
#define DD      64
#define PP      3
#define EE      1600000
#define NPC     98          // coarse partitions of 512 rows: (50000+511)/512
#define CCAP    17664       // slab capacity: mean 16384, sigma 128, +10 sigma
#define NB1     391         // gemm1 row blocks: ceil(50000/128)

typedef __attribute__((ext_vector_type(8))) short short8v;   // 8 bf16 = 4 VGPR
typedef __attribute__((ext_vector_type(4))) float floatx4;
typedef __attribute__((ext_vector_type(2))) float floatx2;

__device__ inline float bfl(uint u) { return __uint_as_float(u << 16); }
__device__ inline float bfh(uint u) { return __uint_as_float(u & 0xffff0000u); }
__device__ inline floatx2 up2(uint u) {          // 2 bf16 -> 2 f32
    floatx2 r; r.x = bfl(u); r.y = bfh(u); return r;
}
__device__ inline uint cvtpk2(float a, float b) {
    __hip_bfloat162 h = __float22bfloat162_rn(make_float2(a, b));
    return *(uint*)&h;
}
__device__ inline ushort f2bf(float x) {
    __hip_bfloat16 h = __float2bfloat16(x);
    return *(ushort*)&h;
}

// ---------------------------------------------------------------------------
// Round W0 [64,1024], Wg [3,64,64], Wa [64,64] to bf16
// ---------------------------------------------------------------------------
__global__ __launch_bounds__(256) void split_weights(const float* __restrict__ W0,
                                                     const float* __restrict__ Wg,
                                                     const float* __restrict__ Wa,
                                                     ushort* __restrict__ W0h,
                                                     ushort* __restrict__ Wgh,
                                                     ushort* __restrict__ Wah)
{
    int i = blockIdx.x * 256 + threadIdx.x;
    if (i < 64 * 1024) W0h[i] = f2bf(W0[i]);
    int j = i - 64 * 1024;
    if (j >= 0 && j < PP * 64 * 64) Wgh[j] = f2bf(Wg[j]);
    int k = i - 64 * 1024 - PP * 64 * 64;
    if (k >= 0 && k < 64 * 64) Wah[k] = f2bf(Wa[k]);
}

// ---------------------------------------------------------------------------
// Barrier-free split-K (x4) h-GEMM quarter. grid (391, 4), 512 threads.
// W0 K-quarter (64x256 bf16 = 32KB, swizzled) in LDS once -> ~4 blocks/CU
// resident (32 waves/CU) and balanced 6 blocks/CU over time.
// Each wave: 16 output rows, A direct global->reg, cvt_pk, MFMA vs LDS B.
// Output: packed fp32 partials [kq][blk][cf][512 thr][4], coalesced.
// ---------------------------------------------------------------------------
__global__ __launch_bounds__(512) void gemm1_partial(const float* __restrict__ feats,
                                                     const ushort* __restrict__ W0h,
                                                     float* __restrict__ hpart)
{
    __shared__ ushort Bh[64 * 256];   // 32 KB: K-quarter of W0
    const int t = threadIdx.x;
    const int w = t >> 6, lane = t & 63;
    const int row0 = blockIdx.x * 128;
    const int kq = blockIdx.y;                   // K-quarter 0..3
    const int l15 = lane & 15, l4 = lane >> 4;

    // load W0 K-quarter into swizzled LDS (one barrier, then free-run)
    #pragma unroll
    for (int rep = 0; rep < 4; ++rep) {
        int id = rep * 512 + t;                  // 0..2047 units of 8 ushorts
        int d = id >> 5, uu = id & 31;
        *(uint4*)&Bh[d * 256 + ((uu ^ (d & 7)) << 3)] =
            *(const uint4*)&W0h[(size_t)d * F_IN + kq * 256 + uu * 8];
    }
    __syncthreads();

    int gr = row0 + w * 16 + l15;
    if (gr >= N_NODES) gr = N_NODES - 1;
    const float* arow = feats + (size_t)gr * F_IN + kq * 256 + l4 * 8;

    floatx4 acc[4] = {};
    #pragma unroll 4
    for (int ks = 0; ks < 8; ++ks) {
        float4 a0 = *(const float4*)&arow[ks * 32];
        float4 a1 = *(const float4*)&arow[ks * 32 + 4];
        uint4 av;
        av.x = cvtpk2(a0.x, a0.y); av.y = cvtpk2(a0.z, a0.w);
        av.z = cvtpk2(a1.x, a1.y); av.w = cvtpk2(a1.z, a1.w);
        short8v ah = *(short8v*)&av;
        int u = ks * 4 + l4;
        #pragma unroll
        for (int cf = 0; cf < 4; ++cf) {
            int d = cf * 16 + l15;
            short8v bh = *(short8v*)&Bh[d * 256 + ((u ^ (d & 7)) << 3)];
            acc[cf] = __builtin_amdgcn_mfma_f32_16x16x32_bf16(ah, bh, acc[cf], 0, 0, 0);
        }
    }

    float* hp = hpart + ((size_t)(kq * NB1 + blockIdx.x)) * 8192;
    #pragma unroll
    for (int cf = 0; cf < 4; ++cf)
        *(float4*)&hp[(cf * 512 + t) * 4] = make_float4(acc[cf][0], acc[cf][1],
                                                        acc[cf][2], acc[cf][3]);
}

// ---------------------------------------------------------------------------
// Combine 4 partials + bias + ELU -> h (bf16, LDS only), then s[p] = h@Wg[p]^T,
// written as [p][half][node][32] bf16 (3.2MB slices for spmm L2 residency),
// via LDS bounce for coalesced stores. grid 782 (64-row tiles).
// ---------------------------------------------------------------------------
__global__ __launch_bounds__(256) void gemm2_combine(const float* __restrict__ hpart,
                                                     const float* __restrict__ b0,
                                                     const ushort* __restrict__ Wgh,
                                                     ushort* __restrict__ s_all)
{
    __shared__ ushort Ah[64 * 64];    // 8 KB  (h tile, swizzled)
    __shared__ ushort Bh[64 * 64];    // 8 KB  (Wg)
    __shared__ ushort Sout[64 * 64];  // 8 KB  (row-major s tile for copy-out)
    const int t = threadIdx.x;
    const int w = t >> 6, lane = t & 63;
    const int row0 = blockIdx.x * 64;
    const int bi = blockIdx.x >> 1;   // gemm1 block
    const int hh = blockIdx.x & 1;    // which 64-row half of the 128-row tile
    const int l15 = lane & 15, l4 = lane >> 4;

    #pragma unroll
    for (int cf = 0; cf < 4; ++cf) {
        int idx = (cf * 512 + hh * 256 + t) * 4;
        float4 a = *(const float4*)&hpart[(size_t)bi * 8192 + idx];
        float4 b = *(const float4*)&hpart[((size_t)NB1 + bi) * 8192 + idx];
        float4 c = *(const float4*)&hpart[((size_t)2 * NB1 + bi) * 8192 + idx];
        float4 d = *(const float4*)&hpart[((size_t)3 * NB1 + bi) * 8192 + idx];
        int col = cf * 16 + l15;
        float bias = b0[col];
        float xs[4] = {a.x + b.x + c.x + d.x + bias, a.y + b.y + c.y + d.y + bias,
                       a.z + b.z + c.z + d.z + bias, a.w + b.w + c.w + d.w + bias};
        #pragma unroll
        for (int r = 0; r < 4; ++r) {
            int row = w * 16 + l4 * 4 + r;       // local row 0..63
            float x = xs[r];
            x = x > 0.f ? x : (__expf(x) - 1.f);
            int u = (col >> 3) ^ (row & 7);
            Ah[row * 64 + u * 8 + (col & 7)] = f2bf(x);
        }
    }
    __syncthreads();

    for (int p = 0; p < PP; ++p) {
        #pragma unroll
        for (int rep = 0; rep < 2; ++rep) {
            int idx = rep * 256 + t;             // 0..511
            int r = idx >> 3, u8 = idx & 7;
            int unit = u8 ^ (r & 7);
            *(uint4*)&Bh[r * 64 + unit * 8] = *(const uint4*)&Wgh[(size_t)p * 4096 + idx * 8];
        }
        __syncthreads();

        floatx4 sacc[4] = {};
        #pragma unroll
        for (int ks = 0; ks < 2; ++ks) {
            int arow2 = w * 16 + l15;
            int au = (ks * 4 + l4) ^ (arow2 & 7);
            short8v ah = *(short8v*)&Ah[arow2 * 64 + au * 8];
            #pragma unroll
            for (int cf = 0; cf < 4; ++cf) {
                int bcol = cf * 16 + l15;
                int bu = (ks * 4 + l4) ^ (bcol & 7);
                short8v bh = *(short8v*)&Bh[bcol * 64 + bu * 8];
                sacc[cf] = __builtin_amdgcn_mfma_f32_16x16x32_bf16(ah, bh, sacc[cf], 0, 0, 0);
            }
        }
        #pragma unroll
        for (int cf = 0; cf < 4; ++cf) {
            int col = cf * 16 + l15;
            #pragma unroll
            for (int r = 0; r < 4; ++r)
                Sout[(w * 16 + l4 * 4 + r) * 64 + col] = f2bf(sacc[cf][r]);
        }
        __syncthreads();
        // coalesced copy-out into [p][half][node][32] slices
        {
            int lr = t >> 2;
            int gr = row0 + lr;
            if (gr < N_NODES) {
                int co = (t & 3) * 16;           // 0,16,32,48
                int half = co >> 5, ci = co & 31;
                ushort* sp = s_all + (size_t)(p * 2 + half) * N_NODES * 32;
                *(uint4*)&sp[(size_t)gr * 32 + ci]     = *(uint4*)&Sout[lr * 64 + co];
                *(uint4*)&sp[(size_t)gr * 32 + ci + 8] = *(uint4*)&Sout[lr * 64 + co + 8];
            }
        }
        __syncthreads();
    }
}

// ---------------------------------------------------------------------------
// part1: bin edges into NPC=98 coarse slabs (512 rows each). grid (625, 3).
// ---------------------------------------------------------------------------
__global__ __launch_bounds__(256) void part1(const int*   __restrict__ rows,
                                             const int*   __restrict__ cols,
                                             const float* __restrict__ vals,
                                             int*   __restrict__ pcur3,
                                             uint2* __restrict__ coarsebuf)
{
    __shared__ uint2 stage[2560];     // 20 KB
    __shared__ uint2 sorted[2560];    // 20 KB
    __shared__ int cnt[128];
    __shared__ int sc[128];
    __shared__ int curb[128];
    __shared__ int gbase[128];
    const int t = threadIdx.x;
    const int path = blockIdx.y;
    const size_t ebase = (size_t)path * EE + (size_t)blockIdx.x * 2560;
    int* pcur = pcur3 + path * NPC;
    uint2* cb = coarsebuf + (size_t)path * NPC * CCAP;

    if (t < 128) { cnt[t] = 0; curb[t] = 0; }
    __syncthreads();

    #pragma unroll
    for (int it = 0; it < 10; ++it) {
        int e = it * 256 + t;
        int r = rows[ebase + e];
        int c = cols[ebase + e];
        float v = vals[ebase + e];
        int bin = r >> 9, rl = r & 511;
        stage[e] = make_uint2((uint)c | ((uint)rl << 16) | ((uint)bin << 25),
                              __float_as_uint(v));
        atomicAdd(&cnt[bin], 1);
    }
    __syncthreads();

    if (t < 128) sc[t] = cnt[t];
    __syncthreads();
    #pragma unroll
    for (int o = 1; o < 128; o <<= 1) {
        int v = (t < 128 && t >= o) ? sc[t - o] : 0;
        __syncthreads();
        if (t < 128 && t >= o) sc[t] += v;
        __syncthreads();
    }

    if (t < NPC) gbase[t] = atomicAdd(&pcur[t], cnt[t]);
    __syncthreads();

    #pragma unroll
    for (int it = 0; it < 10; ++it) {
        uint2 e = stage[it * 256 + t];
        int bin = e.x >> 25;
        int loc = (sc[bin] - cnt[bin]) + atomicAdd(&curb[bin], 1);
        sorted[loc] = e;
    }
    __syncthreads();

    #pragma unroll
    for (int it = 0; it < 10; ++it) {
        int i = it * 256 + t;
        uint2 e = sorted[i];
        int bin = e.x >> 25;
        int g = gbase[bin] + (i - (sc[bin] - cnt[bin]));
        if (g < CCAP) cb[(size_t)bin * CCAP + g] = e;
    }
}

// ---------------------------------------------------------------------------
// sort2: counting-sort each coarse slab by local row (512 bins). grid (98,3).
// Output entries packed to 4B: col(16b) | bf16(val)<<16.
// ---------------------------------------------------------------------------
__global__ __launch_bounds__(512) void sort2(const uint2* __restrict__ coarsebuf,
                                             const int*   __restrict__ pcur3,
                                             uint* __restrict__ sortpk,
                                             int* __restrict__ rowbeg3,
                                             int* __restrict__ rowend3)
{
    __shared__ int hist[512];
    __shared__ int cur[512];
    const int t = threadIdx.x;
    const int c = blockIdx.x, path = blockIdx.y;
    const int n = min(pcur3[path * NPC + c], CCAP);
    const size_t slabbase = ((size_t)path * NPC + c) * CCAP;
    const uint2* src = coarsebuf + slabbase;

    hist[t] = 0;
    __syncthreads();

    for (int i = t; i < n; i += 512)
        atomicAdd(&hist[(src[i].x >> 16) & 511], 1);
    __syncthreads();

    int c0 = hist[t];
    __syncthreads();
    #pragma unroll
    for (int o = 1; o < 512; o <<= 1) {
        int v = (t >= o) ? hist[t - o] : 0;
        __syncthreads();
        hist[t] += v;
        __syncthreads();
    }
    int excl = hist[t] - c0;
    cur[t] = excl;
    int gr = c * 512 + t;
    if (gr < N_NODES) {
        rowbeg3[path * N_NODES + gr] = (int)(slabbase + excl);
        rowend3[path * N_NODES + gr] = (int)(slabbase + excl + c0);
    }
    __syncthreads();

    for (int i = t; i < n; i += 512) {
        uint2 e = src[i];
        int rl = (e.x >> 16) & 511;
        int pos = atomicAdd(&cur[rl], 1);
        sortpk[slabbase + pos] = (e.x & 0xffffu) |
                                 ((uint)f2bf(__uint_as_float(e.y)) << 16);
    }
}

// ---------------------------------------------------------------------------
// Gather SpMM + bias + PReLU: R10 lean loop x R9 L2-resident slicing.
// grid 6*12500, slice-contiguous (slice = path*2 + dim-half; s slice 3.2MB
// stays L2-hot per XCD). One wave per row per slice. lane = (slot<<2)|dq:
// 16 edge slots x 4 dim-octets (16B gathers of the 64B half-row), unroll x2
// -> 32 edges in flight. Clamp-load + select; packed float2 acc.
// ---------------------------------------------------------------------------
__global__ __launch_bounds__(256) void spmm_gather(const uint*   __restrict__ sortpk,
                                                   const int*    __restrict__ rowbeg3,
                                                   const int*    __restrict__ rowend3,
                                                   const ushort* __restrict__ s_all,
                                                   const float*  __restrict__ bg,
                                                   const float*  __restrict__ alpha,
                                                   ushort* __restrict__ emb)
{
    const int slice = blockIdx.x / 12500;        // 0..5 = path*2 + half
    const int path = slice >> 1, half = slice & 1;
    const int wid = (blockIdx.x % 12500) * 4 + (threadIdx.x >> 6);
    const int lane = threadIdx.x & 63;
    const int dq = lane & 3;          // dim-octet within half
    const int slot = lane >> 2;       // 16 edge slots
    const int e0 = rowbeg3[path * N_NODES + wid];
    const int e1 = rowend3[path * N_NODES + wid];
    const ushort* s_p = s_all + (size_t)slice * N_NODES * 32;

    floatx2 acc[4] = {};
    if (e0 < e1) {
        const int last = e1 - 1;
        for (int e = e0; e < e1; e += 32) {
            int ea = e + slot, eb = ea + 16;
            uint pka = sortpk[min(ea, last)];
            uint pkb = sortpk[min(eb, last)];
            const uint4 ga = *(const uint4*)&s_p[(size_t)(pka & 0xffffu) * 32 + dq * 8];
            const uint4 gb = *(const uint4*)&s_p[(size_t)(pkb & 0xffffu) * 32 + dq * 8];
            float va = (ea <= last) ? bfh(pka) : 0.f;
            float vb = (eb <= last) ? bfh(pkb) : 0.f;
            floatx2 va2 = {va, va}, vb2 = {vb, vb};
            acc[0] += va2 * up2(ga.x); acc[1] += va2 * up2(ga.y);
            acc[2] += va2 * up2(ga.z); acc[3] += va2 * up2(ga.w);
            acc[0] += vb2 * up2(gb.x); acc[1] += vb2 * up2(gb.y);
            acc[2] += vb2 * up2(gb.z); acc[3] += vb2 * up2(gb.w);
        }
    }
    // reduce across the 16 slots
    #pragma unroll
    for (int j = 0; j < 4; ++j) {
        acc[j].x += __shfl_xor(acc[j].x, 4);
        acc[j].y += __shfl_xor(acc[j].y, 4);
        acc[j].x += __shfl_xor(acc[j].x, 8);
        acc[j].y += __shfl_xor(acc[j].y, 8);
        acc[j].x += __shfl_xor(acc[j].x, 16);
        acc[j].y += __shfl_xor(acc[j].y, 16);
        acc[j].x += __shfl_xor(acc[j].x, 32);
        acc[j].y += __shfl_xor(acc[j].y, 32);
    }

    if (slot == 0) {   // lanes 0..3 hold dims [half*32 + dq*8, +8)
        const float al = alpha[path];
        const float* bgp = bg + path * 64 + half * 32;
        float x[8];
        #pragma unroll
        for (int j = 0; j < 4; ++j) {
            float v0 = acc[j].x + bgp[dq * 8 + 2 * j];
            float v1 = acc[j].y + bgp[dq * 8 + 2 * j + 1];
            x[2 * j]     = v0 > 0.f ? v0 : al * v0;
            x[2 * j + 1] = v1 > 0.f ? v1 : al * v1;
        }
        uint4 wv;
        wv.x = cvtpk2(x[0], x[1]);
        wv.y = cvtpk2(x[2], x[3]);
        wv.z = cvtpk2(x[4], x[5]);
        wv.w = cvtpk2(x[6], x[7]);
        *(uint4*)&emb[((size_t)path * N_NODES + wid) * 64 + half * 32 + dq * 8] = wv;
    }
}

// ---------------------------------------------------------------------------
// Attention partial sums via MFMA: sp[p] += colsum tanh(emb_p @ Wa^T + ba).
// ---------------------------------------------------------------------------
__global__ __launch_bounds__(256) void postproc(const ushort* __restrict__ emb,
                                                const ushort* __restrict__ Wah,
                                                const float* __restrict__ ba,
                                                float* __restrict__ sp)
{
    __shared__ ushort Ah[64 * 64];
    __shared__ ushort Bh[64 * 64];
    __shared__ float red[16][64];
    const int t = threadIdx.x;
    const int w = t >> 6, lane = t & 63;
    const int l15 = lane & 15, l4 = lane >> 4;
    const int nb = (N_NODES + 63) >> 6;      // 782
    const int p  = blockIdx.x / nb;
    const int tb = blockIdx.x % nb;
    const int row0 = tb * 64;
    const ushort* embp = emb + (size_t)p * N_NODES * 64;

    #pragma unroll
    for (int rep = 0; rep < 2; ++rep) {
        int idx = rep * 256 + t;                 // 0..511
        int r = idx >> 3, u8 = idx & 7;
        int gr = row0 + r; if (gr >= N_NODES) gr = N_NODES - 1;
        int unit = u8 ^ (r & 7);
        *(uint4*)&Ah[r * 64 + unit * 8] = *(const uint4*)&embp[(size_t)gr * 64 + u8 * 8];
        *(uint4*)&Bh[r * 64 + unit * 8] = *(const uint4*)&Wah[idx * 8];
    }
    __syncthreads();

    floatx4 acc[4] = {};
    #pragma unroll
    for (int ks = 0; ks < 2; ++ks) {
        int arow = w * 16 + l15;
        int au = (ks * 4 + l4) ^ (arow & 7);
        short8v ah = *(short8v*)&Ah[arow * 64 + au * 8];
        #pragma unroll
        for (int cf = 0; cf < 4; ++cf) {
            int bcol = cf * 16 + l15;
            int bu = (ks * 4 + l4) ^ (bcol & 7);
            short8v bh = *(short8v*)&Bh[bcol * 64 + bu * 8];
            acc[cf] = __builtin_amdgcn_mfma_f32_16x16x32_bf16(ah, bh, acc[cf], 0, 0, 0);
        }
    }

    #pragma unroll
    for (int cf = 0; cf < 4; ++cf) {
        int col = cf * 16 + l15;
        float s = 0.f;
        #pragma unroll
        for (int r = 0; r < 4; ++r) {
            int gr = row0 + w * 16 + l4 * 4 + r;
            if (gr < N_NODES) s += tanhf(acc[cf][r] + ba[col]);
        }
        red[w * 4 + l4][col] = s;
    }
    __syncthreads();
    if (t < 64) {
        float ssum = 0.f;
        #pragma unroll
        for (int g = 0; g < 16; ++g) ssum += red[g][t];
        unsafeAtomicAdd(&sp[p * 64 + t], ssum);
    }
}

// ---------------------------------------------------------------------------
__global__ void beta_kernel(const float* __restrict__ sp,
                            const float* __restrict__ att,
                            float* __restrict__ beta)
{
    int lane = threadIdx.x;   // 64 threads
    float w[PP];
    #pragma unroll
    for (int p = 0; p < PP; ++p) {
        float x = sp[p * 64 + lane] * (1.0f / (float)N_NODES) * att[lane];
        #pragma unroll
        for (int off = 32; off; off >>= 1) x += __shfl_down(x, off);
        w[p] = __shfl(x, 0);
    }
    if (lane == 0) {
        float mx = fmaxf(w[0], fmaxf(w[1], w[2]));
        float e0 = __expf(w[0] - mx);
        float e1 = __expf(w[1] - mx);
        float e2 = __expf(w[2] - mx);
        float s = e0 + e1 + e2;
        beta[0] = e0 / s; beta[1] = e1 / s; beta[2] = e2 / s;
    }
}

// ---------------------------------------------------------------------------
// z[n][d] = sum_p beta[p] * emb[p][n][d]   (emb bf16, out fp32)
// ---------------------------------------------------------------------------
__global__ __launch_bounds__(256) void combine(const ushort* __restrict__ emb,
                                               const float* __restrict__ beta,
                                               float* __restrict__ out)
{
    const float b0 = beta[0], b1 = beta[1], b2 = beta[2];
    const size_t tot = (size_t)N_NODES * 64;
    size_t i = ((size_t)blockIdx.x * 256 + threadIdx.x) * 8;
    if (i < tot) {
        uint4 e0 = *(const uint4*)&emb[i];
        uint4 e1 = *(const uint4*)&emb[tot + i];
        uint4 e2 = *(const uint4*)&emb[2 * tot + i];
        float o[8];
        o[0] = b0*bfl(e0.x) + b1*bfl(e1.x) + b2*bfl(e2.x);
        o[1] = b0*bfh(e0.x) + b1*bfh(e1.x) + b2*bfh(e2.x);
        o[2] = b0*bfl(e0.y) + b1*bfl(e1.y) + b2*bfl(e2.y);
        o[3] = b0*bfh(e0.y) + b1*bfh(e1.y) + b2*bfh(e2.y);
        o[4] = b0*bfl(e0.z) + b1*bfl(e1.z) + b2*bfl(e2.z);
        o[5] = b0*bfh(e0.z) + b1*bfh(e1.z) + b2*bfh(e2.z);
        o[6] = b0*bfl(e0.w) + b1*bfl(e1.w) + b2*bfl(e2.w);
        o[7] = b0*bfh(e0.w) + b1*bfh(e1.w) + b2*bfh(e2.w);
        *(float4*)&out[i]     = make_float4(o[0], o[1], o[2], o[3]);
        *(float4*)&out[i + 4] = make_float4(o[4], o[5], o[6], o[7]);
    }
}

// ---------------------------------------------------------------------------
extern "C" void kernel_launch(void* const* d_in, const int* in_sizes, int n_in,
                              void* d_out, int out_size, void* d_ws, size_t ws_size,
                              hipStream_t stream)
{
    const float* feats = (const float*)d_in[0];
    const int*   rows  = (const int*)  d_in[1];
    const int*   cols  = (const int*)  d_in[2];
    const float* vals  = (const float*)d_in[3];
    const float* W0    = (const float*)d_in[4];
    const float* b0    = (const float*)d_in[5];
    const float* Wg    = (const float*)d_in[6];
    const float* bg    = (const float*)d_in[7];
    const float* alpha = (const float*)d_in[8];
    const float* Wa    = (const float*)d_in[9];
    const float* ba    = (const float*)d_in[10];
    const float* att   = (const float*)d_in[11];
    float* out = (float*)d_out;

    const size_t ND = (size_t)N_NODES * 64;      // 3.2M elements
    char* base = (char*)d_ws;
    ushort* emb    = (ushort*)base;              base += 3 * ND * 2;        // 19.2 MB
    ushort* s_all  = (ushort*)base;              base += 3 * ND * 2;        // 19.2 MB ([p][half][n][32])
    ushort* W0h    = (ushort*)base;              base += 64 * 1024 * 2;
    ushort* Wgh    = (ushort*)base;              base += PP * 64 * 64 * 2;
    ushort* Wah    = (ushort*)base;              base += 64 * 64 * 2;
    int*    pcur3  = (int*)base;                 base += PP * NPC * 4;
    float*  sp     = (float*)base;               base += 192 * 4;
    float*  beta   = (float*)base;               base += 64 * 4;
    int*    rowbeg3 = (int*)base;                base += PP * N_NODES * 4;  // 600 KB
    int*    rowend3 = (int*)base;                base += PP * N_NODES * 4;  // 600 KB
    base = (char*)(((size_t)base + 255) & ~(size_t)255);
    float*  hpart  = (float*)base;               base += (size_t)4 * NB1 * 8192 * 4;  // 51.2 MB
    uint2*  coarsebuf = (uint2*)base;            base += (size_t)PP * NPC * CCAP * 8; // 41.5 MB
    uint*   sortpk    = (uint*)base;             base += (size_t)PP * NPC * CCAP * 4; // 20.8 MB

    // zero pcur3 + sp (contiguous)
    hipMemsetAsync(pcur3, 0, (PP * NPC + 192) * sizeof(int), stream);

    split_weights<<<(64 * 1024 + PP * 64 * 64 + 64 * 64 + 255) / 256, 256, 0, stream>>>(
        W0, Wg, Wa, W0h, Wgh, Wah);

    gemm1_partial<<<dim3(NB1, 4), 512, 0, stream>>>(feats, W0h, hpart);
    gemm2_combine<<<782, 256, 0, stream>>>(hpart, b0, Wgh, s_all);

    part1<<<dim3(EE / 2560, 3), 256, 0, stream>>>(rows, cols, vals, pcur3, coarsebuf);
    sort2<<<dim3(NPC, 3), 512, 0, stream>>>(coarsebuf, pcur3, sortpk, rowbeg3, rowend3);
    spmm_gather<<<6 * 12500, 256, 0, stream>>>(
        sortpk, rowbeg3, rowend3, s_all, bg, alpha, emb);

    postproc<<<3 * 782, 256, 0, stream>>>(emb, Wah, ba, sp);
    beta_kernel<<<1, 64, 0, stream>>>(sp, att, beta);
    combine<<<(int)((ND / 8 + 255) / 256), 256, 0, stream>>>(emb, beta, out);
}

// Round 16
// 290.106 us; speedup vs baseline: 1.2229x; 1.2229x over previous
//
#include <hip/hip_runtime.h>
#include <hip/hip_bf16.h>

#define N_NODES 50000
#define F_IN    1024
#define DD      64
#define PP      3
#define EE      1600000
#define NPC     98          // coarse partitions of 512 rows: (50000+511)/512
#define CCAP    17664       // slab capacity: mean 16384, sigma 128, +10 sigma
#define NB1     391         // gemm1 row blocks: ceil(50000/128)
#define P1B     625         // part1 blocks per path (2560 edges each)

typedef __attribute__((ext_vector_type(8))) short short8v;   // 8 bf16 = 4 VGPR
typedef __attribute__((ext_vector_type(4))) float floatx4;
typedef __attribute__((ext_vector_type(2))) float floatx2;

__device__ inline float bfl(uint u) { return __uint_as_float(u << 16); }
__device__ inline float bfh(uint u) { return __uint_as_float(u & 0xffff0000u); }
__device__ inline floatx2 up2(uint u) {          // 2 bf16 -> 2 f32
    floatx2 r; r.x = bfl(u); r.y = bfh(u); return r;
}
__device__ inline uint cvtpk2(float a, float b) {
    __hip_bfloat162 h = __float22bfloat162_rn(make_float2(a, b));
    return *(uint*)&h;
}
__device__ inline ushort f2bf(float x) {
    __hip_bfloat16 h = __float2bfloat16(x);
    return *(ushort*)&h;
}

// ---------------------------------------------------------------------------
// Round W0 [64,1024], Wg [3,64,64], Wa [64,64] to bf16
// ---------------------------------------------------------------------------
__global__ __launch_bounds__(256) void split_weights(const float* __restrict__ W0,
                                                     const float* __restrict__ Wg,
                                                     const float* __restrict__ Wa,
                                                     ushort* __restrict__ W0h,
                                                     ushort* __restrict__ Wgh,
                                                     ushort* __restrict__ Wah)
{
    int i = blockIdx.x * 256 + threadIdx.x;
    if (i < 64 * 1024) W0h[i] = f2bf(W0[i]);
    int j = i - 64 * 1024;
    if (j >= 0 && j < PP * 64 * 64) Wgh[j] = f2bf(Wg[j]);
    int k = i - 64 * 1024 - PP * 64 * 64;
    if (k >= 0 && k < 64 * 64) Wah[k] = f2bf(Wa[k]);
}

// ---------------------------------------------------------------------------
// FUSED FRONT: blocks [0, 4*NB1) run split-K(x4) h-GEMM quarters (barrier-
// free, W0 K-quarter 32KB in LDS); blocks [4*NB1, +3*P1B) run part1 edge
// binning (2560 edges/block, 512 threads, LDS counting-sort, coalesced
// flush). Independent workloads overlap on the CU instead of serializing.
// Union LDS = 42KB -> 3 blocks/CU.
// ---------------------------------------------------------------------------
__global__ __launch_bounds__(512) void fused_front(const float* __restrict__ feats,
                                                   const ushort* __restrict__ W0h,
                                                   float* __restrict__ hpart,
                                                   const int*   __restrict__ rows,
                                                   const int*   __restrict__ cols,
                                                   const float* __restrict__ vals,
                                                   int*   __restrict__ pcur3,
                                                   uint2* __restrict__ coarsebuf)
{
    __shared__ __align__(16) char smem[43008];
    const int t = threadIdx.x;

    if (blockIdx.x < 4 * NB1) {
        // ---------------- gemm1_partial role ----------------
        ushort* Bh = (ushort*)smem;          // 64*256 ushorts = 32KB
        const int blk = blockIdx.x;
        const int kq = blk / NB1;            // K-quarter 0..3
        const int bx = blk % NB1;
        const int w = t >> 6, lane = t & 63;
        const int row0 = bx * 128;
        const int l15 = lane & 15, l4 = lane >> 4;

        #pragma unroll
        for (int rep = 0; rep < 4; ++rep) {
            int id = rep * 512 + t;          // 0..2047 units of 8 ushorts
            int d = id >> 5, uu = id & 31;
            *(uint4*)&Bh[d * 256 + ((uu ^ (d & 7)) << 3)] =
                *(const uint4*)&W0h[(size_t)d * F_IN + kq * 256 + uu * 8];
        }
        __syncthreads();

        int gr = row0 + w * 16 + l15;
        if (gr >= N_NODES) gr = N_NODES - 1;
        const float* arow = feats + (size_t)gr * F_IN + kq * 256 + l4 * 8;

        floatx4 acc[4] = {};
        #pragma unroll 4
        for (int ks = 0; ks < 8; ++ks) {
            float4 a0 = *(const float4*)&arow[ks * 32];
            float4 a1 = *(const float4*)&arow[ks * 32 + 4];
            uint4 av;
            av.x = cvtpk2(a0.x, a0.y); av.y = cvtpk2(a0.z, a0.w);
            av.z = cvtpk2(a1.x, a1.y); av.w = cvtpk2(a1.z, a1.w);
            short8v ah = *(short8v*)&av;
            int u = ks * 4 + l4;
            #pragma unroll
            for (int cf = 0; cf < 4; ++cf) {
                int d = cf * 16 + l15;
                short8v bh = *(short8v*)&Bh[d * 256 + ((u ^ (d & 7)) << 3)];
                acc[cf] = __builtin_amdgcn_mfma_f32_16x16x32_bf16(ah, bh, acc[cf], 0, 0, 0);
            }
        }

        float* hp = hpart + ((size_t)(kq * NB1 + bx)) * 8192;
        #pragma unroll
        for (int cf = 0; cf < 4; ++cf)
            *(float4*)&hp[(cf * 512 + t) * 4] = make_float4(acc[cf][0], acc[cf][1],
                                                            acc[cf][2], acc[cf][3]);
    } else {
        // ---------------- part1 role (512 threads) ----------------
        uint2* stage  = (uint2*)smem;                    // 20480 B
        uint2* sorted = (uint2*)(smem + 20480);          // 20480 B
        int*   cnt    = (int*)(smem + 40960);            // 512 B
        int*   sc     = (int*)(smem + 41472);            // 512 B
        int*   curb   = (int*)(smem + 41984);            // 512 B
        int*   gbase  = (int*)(smem + 42496);            // 512 B

        const int pidx = blockIdx.x - 4 * NB1;           // 0..3*P1B-1
        const int path = pidx / P1B;
        const int bx   = pidx % P1B;
        const size_t ebase = (size_t)path * EE + (size_t)bx * 2560;
        int* pcur = pcur3 + path * NPC;
        uint2* cb = coarsebuf + (size_t)path * NPC * CCAP;

        if (t < 128) { cnt[t] = 0; curb[t] = 0; }
        __syncthreads();

        #pragma unroll
        for (int it = 0; it < 5; ++it) {
            int e = it * 512 + t;
            int r = rows[ebase + e];
            int c = cols[ebase + e];
            float v = vals[ebase + e];
            int bin = r >> 9, rl = r & 511;
            stage[e] = make_uint2((uint)c | ((uint)rl << 16) | ((uint)bin << 25),
                                  __float_as_uint(v));
            atomicAdd(&cnt[bin], 1);
        }
        __syncthreads();

        if (t < 128) sc[t] = cnt[t];
        __syncthreads();
        #pragma unroll
        for (int o = 1; o < 128; o <<= 1) {
            int v = (t < 128 && t >= o) ? sc[t - o] : 0;
            __syncthreads();
            if (t < 128 && t >= o) sc[t] += v;
            __syncthreads();
        }

        if (t < NPC) gbase[t] = atomicAdd(&pcur[t], cnt[t]);
        __syncthreads();

        #pragma unroll
        for (int it = 0; it < 5; ++it) {
            uint2 e = stage[it * 512 + t];
            int bin = e.x >> 25;
            int loc = (sc[bin] - cnt[bin]) + atomicAdd(&curb[bin], 1);
            sorted[loc] = e;
        }
        __syncthreads();

        #pragma unroll
        for (int it = 0; it < 5; ++it) {
            int i = it * 512 + t;
            uint2 e = sorted[i];
            int bin = e.x >> 25;
            int g = gbase[bin] + (i - (sc[bin] - cnt[bin]));
            if (g < CCAP) cb[(size_t)bin * CCAP + g] = e;
        }
    }
}

// ---------------------------------------------------------------------------
// Combine 4 partials + bias + ELU -> h (bf16, LDS only), then s[p] = h@Wg[p]^T
// for p=0..2 with LDS-bounced coalesced stores into [p][n][64]. grid 782.
// ---------------------------------------------------------------------------
__global__ __launch_bounds__(256) void gemm2_combine(const float* __restrict__ hpart,
                                                     const float* __restrict__ b0,
                                                     const ushort* __restrict__ Wgh,
                                                     ushort* __restrict__ s_all)
{
    __shared__ ushort Ah[64 * 64];    // 8 KB  (h tile, swizzled)
    __shared__ ushort Bh[64 * 64];    // 8 KB  (Wg)
    __shared__ ushort Sout[64 * 64];  // 8 KB  (row-major s tile for copy-out)
    const int t = threadIdx.x;
    const int w = t >> 6, lane = t & 63;
    const int row0 = blockIdx.x * 64;
    const int bi = blockIdx.x >> 1;   // gemm1 block
    const int hh = blockIdx.x & 1;    // which 64-row half of the 128-row tile
    const int l15 = lane & 15, l4 = lane >> 4;

    #pragma unroll
    for (int cf = 0; cf < 4; ++cf) {
        int idx = (cf * 512 + hh * 256 + t) * 4;
        float4 a = *(const float4*)&hpart[(size_t)bi * 8192 + idx];
        float4 b = *(const float4*)&hpart[((size_t)NB1 + bi) * 8192 + idx];
        float4 c = *(const float4*)&hpart[((size_t)2 * NB1 + bi) * 8192 + idx];
        float4 d = *(const float4*)&hpart[((size_t)3 * NB1 + bi) * 8192 + idx];
        int col = cf * 16 + l15;
        float bias = b0[col];
        float xs[4] = {a.x + b.x + c.x + d.x + bias, a.y + b.y + c.y + d.y + bias,
                       a.z + b.z + c.z + d.z + bias, a.w + b.w + c.w + d.w + bias};
        #pragma unroll
        for (int r = 0; r < 4; ++r) {
            int row = w * 16 + l4 * 4 + r;       // local row 0..63
            float x = xs[r];
            x = x > 0.f ? x : (__expf(x) - 1.f);
            int u = (col >> 3) ^ (row & 7);
            Ah[row * 64 + u * 8 + (col & 7)] = f2bf(x);
        }
    }
    __syncthreads();

    for (int p = 0; p < PP; ++p) {
        #pragma unroll
        for (int rep = 0; rep < 2; ++rep) {
            int idx = rep * 256 + t;             // 0..511
            int r = idx >> 3, u8 = idx & 7;
            int unit = u8 ^ (r & 7);
            *(uint4*)&Bh[r * 64 + unit * 8] = *(const uint4*)&Wgh[(size_t)p * 4096 + idx * 8];
        }
        __syncthreads();

        floatx4 sacc[4] = {};
        #pragma unroll
        for (int ks = 0; ks < 2; ++ks) {
            int arow2 = w * 16 + l15;
            int au = (ks * 4 + l4) ^ (arow2 & 7);
            short8v ah = *(short8v*)&Ah[arow2 * 64 + au * 8];
            #pragma unroll
            for (int cf = 0; cf < 4; ++cf) {
                int bcol = cf * 16 + l15;
                int bu = (ks * 4 + l4) ^ (bcol & 7);
                short8v bh = *(short8v*)&Bh[bcol * 64 + bu * 8];
                sacc[cf] = __builtin_amdgcn_mfma_f32_16x16x32_bf16(ah, bh, sacc[cf], 0, 0, 0);
            }
        }
        #pragma unroll
        for (int cf = 0; cf < 4; ++cf) {
            int col = cf * 16 + l15;
            #pragma unroll
            for (int r = 0; r < 4; ++r)
                Sout[(w * 16 + l4 * 4 + r) * 64 + col] = f2bf(sacc[cf][r]);
        }
        __syncthreads();
        {
            int lr = t >> 2;
            int gr = row0 + lr;
            if (gr < N_NODES) {
                ushort* sp = s_all + (size_t)p * N_NODES * 64;
                int co = (t & 3) * 16;
                *(uint4*)&sp[(size_t)gr * 64 + co]     = *(uint4*)&Sout[lr * 64 + co];
                *(uint4*)&sp[(size_t)gr * 64 + co + 8] = *(uint4*)&Sout[lr * 64 + co + 8];
            }
        }
        __syncthreads();
    }
}

// ---------------------------------------------------------------------------
// sort2: counting-sort each coarse slab by local row (512 bins). grid (98,3).
// Output entries packed to 4B: col(16b) | bf16(val)<<16.
// ---------------------------------------------------------------------------
__global__ __launch_bounds__(512) void sort2(const uint2* __restrict__ coarsebuf,
                                             const int*   __restrict__ pcur3,
                                             uint* __restrict__ sortpk,
                                             int* __restrict__ rowbeg3,
                                             int* __restrict__ rowend3)
{
    __shared__ int hist[512];
    __shared__ int cur[512];
    const int t = threadIdx.x;
    const int c = blockIdx.x, path = blockIdx.y;
    const int n = min(pcur3[path * NPC + c], CCAP);
    const size_t slabbase = ((size_t)path * NPC + c) * CCAP;
    const uint2* src = coarsebuf + slabbase;

    hist[t] = 0;
    __syncthreads();

    for (int i = t; i < n; i += 512)
        atomicAdd(&hist[(src[i].x >> 16) & 511], 1);
    __syncthreads();

    int c0 = hist[t];
    __syncthreads();
    #pragma unroll
    for (int o = 1; o < 512; o <<= 1) {
        int v = (t >= o) ? hist[t - o] : 0;
        __syncthreads();
        hist[t] += v;
        __syncthreads();
    }
    int excl = hist[t] - c0;
    cur[t] = excl;
    int gr = c * 512 + t;
    if (gr < N_NODES) {
        rowbeg3[path * N_NODES + gr] = (int)(slabbase + excl);
        rowend3[path * N_NODES + gr] = (int)(slabbase + excl + c0);
    }
    __syncthreads();

    for (int i = t; i < n; i += 512) {
        uint2 e = src[i];
        int rl = (e.x >> 16) & 511;
        int pos = atomicAdd(&cur[rl], 1);
        sortpk[slabbase + pos] = (e.x & 0xffffu) |
                                 ((uint)f2bf(__uint_as_float(e.y)) << 16);
    }
}

// ---------------------------------------------------------------------------
// Gather SpMM + bias + PReLU (R10-exact, best measured). grid 3*12500,
// path-contiguous. One wave per row; lane = (slot<<3)|dq: 8 edge slots x
// 8 dim-octets (16B gathers), unroll x4 -> 32 edges in flight.
// ---------------------------------------------------------------------------
__global__ __launch_bounds__(256) void spmm_gather(const uint*   __restrict__ sortpk,
                                                   const int*    __restrict__ rowbeg3,
                                                   const int*    __restrict__ rowend3,
                                                   const ushort* __restrict__ s_all,
                                                   const float*  __restrict__ bg,
                                                   const float*  __restrict__ alpha,
                                                   ushort* __restrict__ emb)
{
    const int path = blockIdx.x / 12500;
    const int wid = (blockIdx.x % 12500) * 4 + (threadIdx.x >> 6);
    const int lane = threadIdx.x & 63;
    const int dq = lane & 7;          // dim-octet: dims [dq*8, dq*8+8)
    const int slot = lane >> 3;       // 8 edge slots
    const int e0 = rowbeg3[path * N_NODES + wid];
    const int e1 = rowend3[path * N_NODES + wid];
    const ushort* s_p = s_all + (size_t)path * N_NODES * 64;

    floatx2 acc[4] = {};
    if (e0 < e1) {
        const int last = e1 - 1;
        for (int e = e0; e < e1; e += 32) {
            int ea = e + slot, eb = ea + 8, ec = ea + 16, ed = ea + 24;
            uint pka = sortpk[min(ea, last)];
            uint pkb = sortpk[min(eb, last)];
            uint pkc = sortpk[min(ec, last)];
            uint pkd = sortpk[min(ed, last)];
            const uint4 ga = *(const uint4*)&s_p[(size_t)(pka & 0xffffu) * 64 + dq * 8];
            const uint4 gb = *(const uint4*)&s_p[(size_t)(pkb & 0xffffu) * 64 + dq * 8];
            const uint4 gc = *(const uint4*)&s_p[(size_t)(pkc & 0xffffu) * 64 + dq * 8];
            const uint4 gd = *(const uint4*)&s_p[(size_t)(pkd & 0xffffu) * 64 + dq * 8];
            float va = (ea <= last) ? bfh(pka) : 0.f;
            float vb = (eb <= last) ? bfh(pkb) : 0.f;
            float vc = (ec <= last) ? bfh(pkc) : 0.f;
            float vd = (ed <= last) ? bfh(pkd) : 0.f;
            floatx2 va2 = {va, va}, vb2 = {vb, vb}, vc2 = {vc, vc}, vd2 = {vd, vd};
            acc[0] += va2 * up2(ga.x); acc[1] += va2 * up2(ga.y);
            acc[2] += va2 * up2(ga.z); acc[3] += va2 * up2(ga.w);
            acc[0] += vb2 * up2(gb.x); acc[1] += vb2 * up2(gb.y);
            acc[2] += vb2 * up2(gb.z); acc[3] += vb2 * up2(gb.w);
            acc[0] += vc2 * up2(gc.x); acc[1] += vc2 * up2(gc.y);
            acc[2] += vc2 * up2(gc.z); acc[3] += vc2 * up2(gc.w);
            acc[0] += vd2 * up2(gd.x); acc[1] += vd2 * up2(gd.y);
            acc[2] += vd2 * up2(gd.z); acc[3] += vd2 * up2(gd.w);
        }
    }
    #pragma unroll
    for (int j = 0; j < 4; ++j) {
        acc[j].x += __shfl_xor(acc[j].x, 8);
        acc[j].y += __shfl_xor(acc[j].y, 8);
        acc[j].x += __shfl_xor(acc[j].x, 16);
        acc[j].y += __shfl_xor(acc[j].y, 16);
        acc[j].x += __shfl_xor(acc[j].x, 32);
        acc[j].y += __shfl_xor(acc[j].y, 32);
    }

    if (slot == 0) {
        const float al = alpha[path];
        const float* bgp = bg + path * 64;
        float x[8];
        #pragma unroll
        for (int j = 0; j < 4; ++j) {
            float v0 = acc[j].x + bgp[dq * 8 + 2 * j];
            float v1 = acc[j].y + bgp[dq * 8 + 2 * j + 1];
            x[2 * j]     = v0 > 0.f ? v0 : al * v0;
            x[2 * j + 1] = v1 > 0.f ? v1 : al * v1;
        }
        uint4 wv;
        wv.x = cvtpk2(x[0], x[1]);
        wv.y = cvtpk2(x[2], x[3]);
        wv.z = cvtpk2(x[4], x[5]);
        wv.w = cvtpk2(x[6], x[7]);
        *(uint4*)&emb[((size_t)path * N_NODES + wid) * 64 + dq * 8] = wv;
    }
}

// ---------------------------------------------------------------------------
// Attention partial sums via MFMA: sp[p] += colsum tanh(emb_p @ Wa^T + ba).
// ---------------------------------------------------------------------------
__global__ __launch_bounds__(256) void postproc(const ushort* __restrict__ emb,
                                                const ushort* __restrict__ Wah,
                                                const float* __restrict__ ba,
                                                float* __restrict__ sp)
{
    __shared__ ushort Ah[64 * 64];
    __shared__ ushort Bh[64 * 64];
    __shared__ float red[16][64];
    const int t = threadIdx.x;
    const int w = t >> 6, lane = t & 63;
    const int l15 = lane & 15, l4 = lane >> 4;
    const int nb = (N_NODES + 63) >> 6;      // 782
    const int p  = blockIdx.x / nb;
    const int tb = blockIdx.x % nb;
    const int row0 = tb * 64;
    const ushort* embp = emb + (size_t)p * N_NODES * 64;

    #pragma unroll
    for (int rep = 0; rep < 2; ++rep) {
        int idx = rep * 256 + t;                 // 0..511
        int r = idx >> 3, u8 = idx & 7;
        int gr = row0 + r; if (gr >= N_NODES) gr = N_NODES - 1;
        int unit = u8 ^ (r & 7);
        *(uint4*)&Ah[r * 64 + unit * 8] = *(const uint4*)&embp[(size_t)gr * 64 + u8 * 8];
        *(uint4*)&Bh[r * 64 + unit * 8] = *(const uint4*)&Wah[idx * 8];
    }
    __syncthreads();

    floatx4 acc[4] = {};
    #pragma unroll
    for (int ks = 0; ks < 2; ++ks) {
        int arow = w * 16 + l15;
        int au = (ks * 4 + l4) ^ (arow & 7);
        short8v ah = *(short8v*)&Ah[arow * 64 + au * 8];
        #pragma unroll
        for (int cf = 0; cf < 4; ++cf) {
            int bcol = cf * 16 + l15;
            int bu = (ks * 4 + l4) ^ (bcol & 7);
            short8v bh = *(short8v*)&Bh[bcol * 64 + bu * 8];
            acc[cf] = __builtin_amdgcn_mfma_f32_16x16x32_bf16(ah, bh, acc[cf], 0, 0, 0);
        }
    }

    #pragma unroll
    for (int cf = 0; cf < 4; ++cf) {
        int col = cf * 16 + l15;
        float s = 0.f;
        #pragma unroll
        for (int r = 0; r < 4; ++r) {
            int gr = row0 + w * 16 + l4 * 4 + r;
            if (gr < N_NODES) s += tanhf(acc[cf][r] + ba[col]);
        }
        red[w * 4 + l4][col] = s;
    }
    __syncthreads();
    if (t < 64) {
        float ssum = 0.f;
        #pragma unroll
        for (int g = 0; g < 16; ++g) ssum += red[g][t];
        unsafeAtomicAdd(&sp[p * 64 + t], ssum);
    }
}

// ---------------------------------------------------------------------------
__global__ void beta_kernel(const float* __restrict__ sp,
                            const float* __restrict__ att,
                            float* __restrict__ beta)
{
    int lane = threadIdx.x;   // 64 threads
    float w[PP];
    #pragma unroll
    for (int p = 0; p < PP; ++p) {
        float x = sp[p * 64 + lane] * (1.0f / (float)N_NODES) * att[lane];
        #pragma unroll
        for (int off = 32; off; off >>= 1) x += __shfl_down(x, off);
        w[p] = __shfl(x, 0);
    }
    if (lane == 0) {
        float mx = fmaxf(w[0], fmaxf(w[1], w[2]));
        float e0 = __expf(w[0] - mx);
        float e1 = __expf(w[1] - mx);
        float e2 = __expf(w[2] - mx);
        float s = e0 + e1 + e2;
        beta[0] = e0 / s; beta[1] = e1 / s; beta[2] = e2 / s;
    }
}

// ---------------------------------------------------------------------------
// z[n][d] = sum_p beta[p] * emb[p][n][d]   (emb bf16, out fp32)
// ---------------------------------------------------------------------------
__global__ __launch_bounds__(256) void combine(const ushort* __restrict__ emb,
                                               const float* __restrict__ beta,
                                               float* __restrict__ out)
{
    const float b0 = beta[0], b1 = beta[1], b2 = beta[2];
    const size_t tot = (size_t)N_NODES * 64;
    size_t i = ((size_t)blockIdx.x * 256 + threadIdx.x) * 8;
    if (i < tot) {
        uint4 e0 = *(const uint4*)&emb[i];
        uint4 e1 = *(const uint4*)&emb[tot + i];
        uint4 e2 = *(const uint4*)&emb[2 * tot + i];
        float o[8];
        o[0] = b0*bfl(e0.x) + b1*bfl(e1.x) + b2*bfl(e2.x);
        o[1] = b0*bfh(e0.x) + b1*bfh(e1.x) + b2*bfh(e2.x);
        o[2] = b0*bfl(e0.y) + b1*bfl(e1.y) + b2*bfl(e2.y);
        o[3] = b0*bfh(e0.y) + b1*bfh(e1.y) + b2*bfh(e2.y);
        o[4] = b0*bfl(e0.z) + b1*bfl(e1.z) + b2*bfl(e2.z);
        o[5] = b0*bfh(e0.z) + b1*bfh(e1.z) + b2*bfh(e2.z);
        o[6] = b0*bfl(e0.w) + b1*bfl(e1.w) + b2*bfl(e2.w);
        o[7] = b0*bfh(e0.w) + b1*bfh(e1.w) + b2*bfh(e2.w);
        *(float4*)&out[i]     = make_float4(o[0], o[1], o[2], o[3]);
        *(float4*)&out[i + 4] = make_float4(o[4], o[5], o[6], o[7]);
    }
}

// ---------------------------------------------------------------------------
extern "C" void kernel_launch(void* const* d_in, const int* in_sizes, int n_in,
                              void* d_out, int out_size, void* d_ws, size_t ws_size,
                              hipStream_t stream)
{
    const float* feats = (const float*)d_in[0];
    const int*   rows  = (const int*)  d_in[1];
    const int*   cols  = (const int*)  d_in[2];
    const float* vals  = (const float*)d_in[3];
    const float* W0    = (const float*)d_in[4];
    const float* b0    = (const float*)d_in[5];
    const float* Wg    = (const float*)d_in[6];
    const float* bg    = (const float*)d_in[7];
    const float* alpha = (const float*)d_in[8];
    const float* Wa    = (const float*)d_in[9];
    const float* ba    = (const float*)d_in[10];
    const float* att   = (const float*)d_in[11];
    float* out = (float*)d_out;

    const size_t ND = (size_t)N_NODES * 64;      // 3.2M elements
    char* base = (char*)d_ws;
    ushort* emb    = (ushort*)base;              base += 3 * ND * 2;        // 19.2 MB
    ushort* s_all  = (ushort*)base;              base += 3 * ND * 2;        // 19.2 MB ([p][n][64])
    ushort* W0h    = (ushort*)base;              base += 64 * 1024 * 2;
    ushort* Wgh    = (ushort*)base;              base += PP * 64 * 64 * 2;
    ushort* Wah    = (ushort*)base;              base += 64 * 64 * 2;
    int*    pcur3  = (int*)base;                 base += PP * NPC * 4;
    float*  sp     = (float*)base;               base += 192 * 4;
    float*  beta   = (float*)base;               base += 64 * 4;
    int*    rowbeg3 = (int*)base;                base += PP * N_NODES * 4;  // 600 KB
    int*    rowend3 = (int*)base;                base += PP * N_NODES * 4;  // 600 KB
    base = (char*)(((size_t)base + 255) & ~(size_t)255);
    float*  hpart  = (float*)base;               base += (size_t)4 * NB1 * 8192 * 4;  // 51.2 MB
    uint2*  coarsebuf = (uint2*)base;            base += (size_t)PP * NPC * CCAP * 8; // 41.5 MB
    uint*   sortpk    = (uint*)base;             base += (size_t)PP * NPC * CCAP * 4; // 20.8 MB

    // zero pcur3 + sp (contiguous)
    hipMemsetAsync(pcur3, 0, (PP * NPC + 192) * sizeof(int), stream);

    split_weights<<<(64 * 1024 + PP * 64 * 64 + 64 * 64 + 255) / 256, 256, 0, stream>>>(
        W0, Wg, Wa, W0h, Wgh, Wah);

    // fused: gemm1 split-K(x4) + part1 edge binning, overlapped
    fused_front<<<4 * NB1 + 3 * P1B, 512, 0, stream>>>(
        feats, W0h, hpart, rows, cols, vals, pcur3, coarsebuf);

    gemm2_combine<<<782, 256, 0, stream>>>(hpart, b0, Wgh, s_all);
    sort2<<<dim3(NPC, 3), 512, 0, stream>>>(coarsebuf, pcur3, sortpk, rowbeg3, rowend3);
    spmm_gather<<<3 * 12500, 256, 0, stream>>>(
        sortpk, rowbeg3, rowend3, s_all, bg, alpha, emb);

    postproc<<<3 * 782, 256, 0, stream>>>(emb, Wah, ba, sp);
    beta_kernel<<<1, 64, 0, stream>>>(sp, att, beta);
    combine<<<(int)((ND / 8 + 255) / 256), 256, 0, stream>>>(emb, beta, out);
}

// Round 17
// 274.280 us; speedup vs baseline: 1.2935x; 1.0577x over previous
//
#include <hip/hip_runtime.h>
#include <hip/hip_bf16.h>

#define N_NODES 50000
#define F_IN    1024
#define DD      64
#define PP      3
#define EE      1600000
#define NPC     98          // coarse partitions of 512 rows: (50000+511)/512
#define CCAP    17664       // slab capacity: mean 16384, sigma 128, +10 sigma
#define NB1     391         // gemm1 row blocks: ceil(50000/128)
#define P1B     625         // part1 blocks per path (2560 edges each)
#define GEMM1B  (4 * NB1)   // 1564
#define PART1B  (3 * P1B)   // 1875

typedef __attribute__((ext_vector_type(8))) short short8v;   // 8 bf16 = 4 VGPR
typedef __attribute__((ext_vector_type(4))) float floatx4;
typedef __attribute__((ext_vector_type(2))) float floatx2;

__device__ inline float bfl(uint u) { return __uint_as_float(u << 16); }
__device__ inline float bfh(uint u) { return __uint_as_float(u & 0xffff0000u); }
__device__ inline floatx2 up2(uint u) {          // 2 bf16 -> 2 f32
    floatx2 r; r.x = bfl(u); r.y = bfh(u); return r;
}
__device__ inline uint cvtpk2(float a, float b) {
    __hip_bfloat162 h = __float22bfloat162_rn(make_float2(a, b));
    return *(uint*)&h;
}
__device__ inline ushort f2bf(float x) {
    __hip_bfloat16 h = __float2bfloat16(x);
    return *(ushort*)&h;
}

// ---------------------------------------------------------------------------
// Round W0 [64,1024], Wg [3,64,64], Wa [64,64] to bf16
// ---------------------------------------------------------------------------
__global__ __launch_bounds__(256) void split_weights(const float* __restrict__ W0,
                                                     const float* __restrict__ Wg,
                                                     const float* __restrict__ Wa,
                                                     ushort* __restrict__ W0h,
                                                     ushort* __restrict__ Wgh,
                                                     ushort* __restrict__ Wah)
{
    int i = blockIdx.x * 256 + threadIdx.x;
    if (i < 64 * 1024) W0h[i] = f2bf(W0[i]);
    int j = i - 64 * 1024;
    if (j >= 0 && j < PP * 64 * 64) Wgh[j] = f2bf(Wg[j]);
    int k = i - 64 * 1024 - PP * 64 * 64;
    if (k >= 0 && k < 64 * 64) Wah[k] = f2bf(Wa[k]);
}

// ---------------------------------------------------------------------------
// FUSED FRONT with INTERLEAVED roles: even blocks < 2*GEMM1B run split-K(x4)
// h-GEMM quarters; all others run part1 edge binning. Interleaving keeps a
// BW-bound and a latency-bound block co-resident on each CU for the entire
// dispatch (time ~= max, not sum).
// ---------------------------------------------------------------------------
__global__ __launch_bounds__(512) void fused_front(const float* __restrict__ feats,
                                                   const ushort* __restrict__ W0h,
                                                   float* __restrict__ hpart,
                                                   const int*   __restrict__ rows,
                                                   const int*   __restrict__ cols,
                                                   const float* __restrict__ vals,
                                                   int*   __restrict__ pcur3,
                                                   uint2* __restrict__ coarsebuf)
{
    __shared__ __align__(16) char smem[43008];
    const int t = threadIdx.x;
    const int bid = blockIdx.x;
    const bool is_gemm = (bid < 2 * GEMM1B) && ((bid & 1) == 0);

    if (is_gemm) {
        // ---------------- gemm1_partial role ----------------
        ushort* Bh = (ushort*)smem;          // 64*256 ushorts = 32KB
        const int blk = bid >> 1;            // 0..GEMM1B-1
        const int kq = blk / NB1;            // K-quarter 0..3
        const int bx = blk % NB1;
        const int w = t >> 6, lane = t & 63;
        const int row0 = bx * 128;
        const int l15 = lane & 15, l4 = lane >> 4;

        #pragma unroll
        for (int rep = 0; rep < 4; ++rep) {
            int id = rep * 512 + t;          // 0..2047 units of 8 ushorts
            int d = id >> 5, uu = id & 31;
            *(uint4*)&Bh[d * 256 + ((uu ^ (d & 7)) << 3)] =
                *(const uint4*)&W0h[(size_t)d * F_IN + kq * 256 + uu * 8];
        }
        __syncthreads();

        int gr = row0 + w * 16 + l15;
        if (gr >= N_NODES) gr = N_NODES - 1;
        const float* arow = feats + (size_t)gr * F_IN + kq * 256 + l4 * 8;

        floatx4 acc[4] = {};
        #pragma unroll 4
        for (int ks = 0; ks < 8; ++ks) {
            float4 a0 = *(const float4*)&arow[ks * 32];
            float4 a1 = *(const float4*)&arow[ks * 32 + 4];
            uint4 av;
            av.x = cvtpk2(a0.x, a0.y); av.y = cvtpk2(a0.z, a0.w);
            av.z = cvtpk2(a1.x, a1.y); av.w = cvtpk2(a1.z, a1.w);
            short8v ah = *(short8v*)&av;
            int u = ks * 4 + l4;
            #pragma unroll
            for (int cf = 0; cf < 4; ++cf) {
                int d = cf * 16 + l15;
                short8v bh = *(short8v*)&Bh[d * 256 + ((u ^ (d & 7)) << 3)];
                acc[cf] = __builtin_amdgcn_mfma_f32_16x16x32_bf16(ah, bh, acc[cf], 0, 0, 0);
            }
        }

        float* hp = hpart + ((size_t)(kq * NB1 + bx)) * 8192;
        #pragma unroll
        for (int cf = 0; cf < 4; ++cf)
            *(float4*)&hp[(cf * 512 + t) * 4] = make_float4(acc[cf][0], acc[cf][1],
                                                            acc[cf][2], acc[cf][3]);
    } else {
        // ---------------- part1 role (512 threads) ----------------
        uint2* stage  = (uint2*)smem;                    // 20480 B
        uint2* sorted = (uint2*)(smem + 20480);          // 20480 B
        int*   cnt    = (int*)(smem + 40960);            // 512 B
        int*   sc     = (int*)(smem + 41472);            // 512 B
        int*   curb   = (int*)(smem + 41984);            // 512 B
        int*   gbase  = (int*)(smem + 42496);            // 512 B

        // bijective part1 index: odd blocks < 2*GEMM1B -> bid>>1;
        // blocks >= 2*GEMM1B -> bid - GEMM1B
        const int pidx = (bid < 2 * GEMM1B) ? (bid >> 1) : (bid - GEMM1B);
        const int path = pidx / P1B;
        const int bx   = pidx % P1B;
        const size_t ebase = (size_t)path * EE + (size_t)bx * 2560;
        int* pcur = pcur3 + path * NPC;
        uint2* cb = coarsebuf + (size_t)path * NPC * CCAP;

        if (t < 128) { cnt[t] = 0; curb[t] = 0; }
        __syncthreads();

        #pragma unroll
        for (int it = 0; it < 5; ++it) {
            int e = it * 512 + t;
            int r = rows[ebase + e];
            int c = cols[ebase + e];
            float v = vals[ebase + e];
            int bin = r >> 9, rl = r & 511;
            stage[e] = make_uint2((uint)c | ((uint)rl << 16) | ((uint)bin << 25),
                                  __float_as_uint(v));
            atomicAdd(&cnt[bin], 1);
        }
        __syncthreads();

        if (t < 128) sc[t] = cnt[t];
        __syncthreads();
        #pragma unroll
        for (int o = 1; o < 128; o <<= 1) {
            int v = (t < 128 && t >= o) ? sc[t - o] : 0;
            __syncthreads();
            if (t < 128 && t >= o) sc[t] += v;
            __syncthreads();
        }

        if (t < NPC) gbase[t] = atomicAdd(&pcur[t], cnt[t]);
        __syncthreads();

        #pragma unroll
        for (int it = 0; it < 5; ++it) {
            uint2 e = stage[it * 512 + t];
            int bin = e.x >> 25;
            int loc = (sc[bin] - cnt[bin]) + atomicAdd(&curb[bin], 1);
            sorted[loc] = e;
        }
        __syncthreads();

        #pragma unroll
        for (int it = 0; it < 5; ++it) {
            int i = it * 512 + t;
            uint2 e = sorted[i];
            int bin = e.x >> 25;
            int g = gbase[bin] + (i - (sc[bin] - cnt[bin]));
            if (g < CCAP) cb[(size_t)bin * CCAP + g] = e;
        }
    }
}

// ---------------------------------------------------------------------------
// FUSED MID: blocks [0, NB1) = gemm2_combine (512 thr, two 64-row sub-tiles
// of one 128-row gemm1 block); blocks [NB1, NB1+294) = sort2. Independent
// workloads (both depend only on fused_front) overlap on the CU.
// ---------------------------------------------------------------------------
__global__ __launch_bounds__(512) void fused_mid(const float* __restrict__ hpart,
                                                 const float* __restrict__ b0,
                                                 const ushort* __restrict__ Wgh,
                                                 ushort* __restrict__ s_all,
                                                 const uint2* __restrict__ coarsebuf,
                                                 const int*   __restrict__ pcur3,
                                                 uint* __restrict__ sortpk,
                                                 int* __restrict__ rowbeg3,
                                                 int* __restrict__ rowend3)
{
    __shared__ __align__(16) char smem[40960];
    const int t = threadIdx.x;
    const int bid = blockIdx.x;

    if (bid < NB1) {
        // ---------------- gemm2_combine role ----------------
        ushort* Ah   = (ushort*)smem;                    // 2 x 64*64 = 16KB
        ushort* Bh   = (ushort*)(smem + 16384);          // 8KB (shared by subs)
        ushort* Sout = (ushort*)(smem + 24576);          // 2 x 64*64 = 16KB
        const int sub = t >> 8;          // 0/1: which 64-row half
        const int tt  = t & 255;
        const int w = tt >> 6, lane = tt & 63;
        const int l15 = lane & 15, l4 = lane >> 4;
        const int bi = bid;
        const int row0 = bi * 128 + sub * 64;
        ushort* Ahs = Ah + sub * 4096;
        ushort* Souts = Sout + sub * 4096;

        #pragma unroll
        for (int cf = 0; cf < 4; ++cf) {
            int idx = (cf * 512 + sub * 256 + tt) * 4;
            float4 a = *(const float4*)&hpart[(size_t)bi * 8192 + idx];
            float4 b = *(const float4*)&hpart[((size_t)NB1 + bi) * 8192 + idx];
            float4 c = *(const float4*)&hpart[((size_t)2 * NB1 + bi) * 8192 + idx];
            float4 d = *(const float4*)&hpart[((size_t)3 * NB1 + bi) * 8192 + idx];
            int col = cf * 16 + l15;
            float bias = b0[col];
            float xs[4] = {a.x + b.x + c.x + d.x + bias, a.y + b.y + c.y + d.y + bias,
                           a.z + b.z + c.z + d.z + bias, a.w + b.w + c.w + d.w + bias};
            #pragma unroll
            for (int r = 0; r < 4; ++r) {
                int row = w * 16 + l4 * 4 + r;   // local row 0..63
                float x = xs[r];
                x = x > 0.f ? x : (__expf(x) - 1.f);
                int u = (col >> 3) ^ (row & 7);
                Ahs[row * 64 + u * 8 + (col & 7)] = f2bf(x);
            }
        }
        __syncthreads();

        for (int p = 0; p < PP; ++p) {
            // load Wg[p] (512 threads, once)
            {
                int r = t >> 3, u8 = t & 7;
                int unit = u8 ^ (r & 7);
                *(uint4*)&Bh[r * 64 + unit * 8] =
                    *(const uint4*)&Wgh[(size_t)p * 4096 + t * 8];
            }
            __syncthreads();

            floatx4 sacc[4] = {};
            #pragma unroll
            for (int ks = 0; ks < 2; ++ks) {
                int arow2 = w * 16 + l15;
                int au = (ks * 4 + l4) ^ (arow2 & 7);
                short8v ah = *(short8v*)&Ahs[arow2 * 64 + au * 8];
                #pragma unroll
                for (int cf = 0; cf < 4; ++cf) {
                    int bcol = cf * 16 + l15;
                    int bu = (ks * 4 + l4) ^ (bcol & 7);
                    short8v bh = *(short8v*)&Bh[bcol * 64 + bu * 8];
                    sacc[cf] = __builtin_amdgcn_mfma_f32_16x16x32_bf16(ah, bh, sacc[cf], 0, 0, 0);
                }
            }
            #pragma unroll
            for (int cf = 0; cf < 4; ++cf) {
                int col = cf * 16 + l15;
                #pragma unroll
                for (int r = 0; r < 4; ++r)
                    Souts[(w * 16 + l4 * 4 + r) * 64 + col] = f2bf(sacc[cf][r]);
            }
            __syncthreads();
            {
                int lr = tt >> 2;
                int gr = row0 + lr;
                if (gr < N_NODES) {
                    ushort* sp = s_all + (size_t)p * N_NODES * 64;
                    int co = (tt & 3) * 16;
                    *(uint4*)&sp[(size_t)gr * 64 + co]     = *(uint4*)&Souts[lr * 64 + co];
                    *(uint4*)&sp[(size_t)gr * 64 + co + 8] = *(uint4*)&Souts[lr * 64 + co + 8];
                }
            }
            __syncthreads();
        }
    } else {
        // ---------------- sort2 role ----------------
        int* hist = (int*)smem;           // 2KB
        int* cur  = (int*)(smem + 2048);  // 2KB
        const int sidx = bid - NB1;       // 0..293
        const int c = sidx % NPC, path = sidx / NPC;
        const int n = min(pcur3[path * NPC + c], CCAP);
        const size_t slabbase = ((size_t)path * NPC + c) * CCAP;
        const uint2* src = coarsebuf + slabbase;

        hist[t] = 0;
        __syncthreads();

        for (int i = t; i < n; i += 512)
            atomicAdd(&hist[(src[i].x >> 16) & 511], 1);
        __syncthreads();

        int c0 = hist[t];
        __syncthreads();
        #pragma unroll
        for (int o = 1; o < 512; o <<= 1) {
            int v = (t >= o) ? hist[t - o] : 0;
            __syncthreads();
            hist[t] += v;
            __syncthreads();
        }
        int excl = hist[t] - c0;
        cur[t] = excl;
        int gr = c * 512 + t;
        if (gr < N_NODES) {
            rowbeg3[path * N_NODES + gr] = (int)(slabbase + excl);
            rowend3[path * N_NODES + gr] = (int)(slabbase + excl + c0);
        }
        __syncthreads();

        for (int i = t; i < n; i += 512) {
            uint2 e = src[i];
            int rl = (e.x >> 16) & 511;
            int pos = atomicAdd(&cur[rl], 1);
            sortpk[slabbase + pos] = (e.x & 0xffffu) |
                                     ((uint)f2bf(__uint_as_float(e.y)) << 16);
        }
    }
}

// ---------------------------------------------------------------------------
// Gather SpMM + bias + PReLU (R10-exact, best measured). grid 3*12500.
// ---------------------------------------------------------------------------
__global__ __launch_bounds__(256) void spmm_gather(const uint*   __restrict__ sortpk,
                                                   const int*    __restrict__ rowbeg3,
                                                   const int*    __restrict__ rowend3,
                                                   const ushort* __restrict__ s_all,
                                                   const float*  __restrict__ bg,
                                                   const float*  __restrict__ alpha,
                                                   ushort* __restrict__ emb)
{
    const int path = blockIdx.x / 12500;
    const int wid = (blockIdx.x % 12500) * 4 + (threadIdx.x >> 6);
    const int lane = threadIdx.x & 63;
    const int dq = lane & 7;          // dim-octet: dims [dq*8, dq*8+8)
    const int slot = lane >> 3;       // 8 edge slots
    const int e0 = rowbeg3[path * N_NODES + wid];
    const int e1 = rowend3[path * N_NODES + wid];
    const ushort* s_p = s_all + (size_t)path * N_NODES * 64;

    floatx2 acc[4] = {};
    if (e0 < e1) {
        const int last = e1 - 1;
        for (int e = e0; e < e1; e += 32) {
            int ea = e + slot, eb = ea + 8, ec = ea + 16, ed = ea + 24;
            uint pka = sortpk[min(ea, last)];
            uint pkb = sortpk[min(eb, last)];
            uint pkc = sortpk[min(ec, last)];
            uint pkd = sortpk[min(ed, last)];
            const uint4 ga = *(const uint4*)&s_p[(size_t)(pka & 0xffffu) * 64 + dq * 8];
            const uint4 gb = *(const uint4*)&s_p[(size_t)(pkb & 0xffffu) * 64 + dq * 8];
            const uint4 gc = *(const uint4*)&s_p[(size_t)(pkc & 0xffffu) * 64 + dq * 8];
            const uint4 gd = *(const uint4*)&s_p[(size_t)(pkd & 0xffffu) * 64 + dq * 8];
            float va = (ea <= last) ? bfh(pka) : 0.f;
            float vb = (eb <= last) ? bfh(pkb) : 0.f;
            float vc = (ec <= last) ? bfh(pkc) : 0.f;
            float vd = (ed <= last) ? bfh(pkd) : 0.f;
            floatx2 va2 = {va, va}, vb2 = {vb, vb}, vc2 = {vc, vc}, vd2 = {vd, vd};
            acc[0] += va2 * up2(ga.x); acc[1] += va2 * up2(ga.y);
            acc[2] += va2 * up2(ga.z); acc[3] += va2 * up2(ga.w);
            acc[0] += vb2 * up2(gb.x); acc[1] += vb2 * up2(gb.y);
            acc[2] += vb2 * up2(gb.z); acc[3] += vb2 * up2(gb.w);
            acc[0] += vc2 * up2(gc.x); acc[1] += vc2 * up2(gc.y);
            acc[2] += vc2 * up2(gc.z); acc[3] += vc2 * up2(gc.w);
            acc[0] += vd2 * up2(gd.x); acc[1] += vd2 * up2(gd.y);
            acc[2] += vd2 * up2(gd.z); acc[3] += vd2 * up2(gd.w);
        }
    }
    #pragma unroll
    for (int j = 0; j < 4; ++j) {
        acc[j].x += __shfl_xor(acc[j].x, 8);
        acc[j].y += __shfl_xor(acc[j].y, 8);
        acc[j].x += __shfl_xor(acc[j].x, 16);
        acc[j].y += __shfl_xor(acc[j].y, 16);
        acc[j].x += __shfl_xor(acc[j].x, 32);
        acc[j].y += __shfl_xor(acc[j].y, 32);
    }

    if (slot == 0) {
        const float al = alpha[path];
        const float* bgp = bg + path * 64;
        float x[8];
        #pragma unroll
        for (int j = 0; j < 4; ++j) {
            float v0 = acc[j].x + bgp[dq * 8 + 2 * j];
            float v1 = acc[j].y + bgp[dq * 8 + 2 * j + 1];
            x[2 * j]     = v0 > 0.f ? v0 : al * v0;
            x[2 * j + 1] = v1 > 0.f ? v1 : al * v1;
        }
        uint4 wv;
        wv.x = cvtpk2(x[0], x[1]);
        wv.y = cvtpk2(x[2], x[3]);
        wv.z = cvtpk2(x[4], x[5]);
        wv.w = cvtpk2(x[6], x[7]);
        *(uint4*)&emb[((size_t)path * N_NODES + wid) * 64 + dq * 8] = wv;
    }
}

// ---------------------------------------------------------------------------
// Attention partial sums via MFMA: sp[p] += colsum tanh(emb_p @ Wa^T + ba).
// ---------------------------------------------------------------------------
__global__ __launch_bounds__(256) void postproc(const ushort* __restrict__ emb,
                                                const ushort* __restrict__ Wah,
                                                const float* __restrict__ ba,
                                                float* __restrict__ sp)
{
    __shared__ ushort Ah[64 * 64];
    __shared__ ushort Bh[64 * 64];
    __shared__ float red[16][64];
    const int t = threadIdx.x;
    const int w = t >> 6, lane = t & 63;
    const int l15 = lane & 15, l4 = lane >> 4;
    const int nb = (N_NODES + 63) >> 6;      // 782
    const int p  = blockIdx.x / nb;
    const int tb = blockIdx.x % nb;
    const int row0 = tb * 64;
    const ushort* embp = emb + (size_t)p * N_NODES * 64;

    #pragma unroll
    for (int rep = 0; rep < 2; ++rep) {
        int idx = rep * 256 + t;                 // 0..511
        int r = idx >> 3, u8 = idx & 7;
        int gr = row0 + r; if (gr >= N_NODES) gr = N_NODES - 1;
        int unit = u8 ^ (r & 7);
        *(uint4*)&Ah[r * 64 + unit * 8] = *(const uint4*)&embp[(size_t)gr * 64 + u8 * 8];
        *(uint4*)&Bh[r * 64 + unit * 8] = *(const uint4*)&Wah[idx * 8];
    }
    __syncthreads();

    floatx4 acc[4] = {};
    #pragma unroll
    for (int ks = 0; ks < 2; ++ks) {
        int arow = w * 16 + l15;
        int au = (ks * 4 + l4) ^ (arow & 7);
        short8v ah = *(short8v*)&Ah[arow * 64 + au * 8];
        #pragma unroll
        for (int cf = 0; cf < 4; ++cf) {
            int bcol = cf * 16 + l15;
            int bu = (ks * 4 + l4) ^ (bcol & 7);
            short8v bh = *(short8v*)&Bh[bcol * 64 + bu * 8];
            acc[cf] = __builtin_amdgcn_mfma_f32_16x16x32_bf16(ah, bh, acc[cf], 0, 0, 0);
        }
    }

    #pragma unroll
    for (int cf = 0; cf < 4; ++cf) {
        int col = cf * 16 + l15;
        float s = 0.f;
        #pragma unroll
        for (int r = 0; r < 4; ++r) {
            int gr = row0 + w * 16 + l4 * 4 + r;
            if (gr < N_NODES) s += tanhf(acc[cf][r] + ba[col]);
        }
        red[w * 4 + l4][col] = s;
    }
    __syncthreads();
    if (t < 64) {
        float ssum = 0.f;
        #pragma unroll
        for (int g = 0; g < 16; ++g) ssum += red[g][t];
        unsafeAtomicAdd(&sp[p * 64 + t], ssum);
    }
}

// ---------------------------------------------------------------------------
__global__ void beta_kernel(const float* __restrict__ sp,
                            const float* __restrict__ att,
                            float* __restrict__ beta)
{
    int lane = threadIdx.x;   // 64 threads
    float w[PP];
    #pragma unroll
    for (int p = 0; p < PP; ++p) {
        float x = sp[p * 64 + lane] * (1.0f / (float)N_NODES) * att[lane];
        #pragma unroll
        for (int off = 32; off; off >>= 1) x += __shfl_down(x, off);
        w[p] = __shfl(x, 0);
    }
    if (lane == 0) {
        float mx = fmaxf(w[0], fmaxf(w[1], w[2]));
        float e0 = __expf(w[0] - mx);
        float e1 = __expf(w[1] - mx);
        float e2 = __expf(w[2] - mx);
        float s = e0 + e1 + e2;
        beta[0] = e0 / s; beta[1] = e1 / s; beta[2] = e2 / s;
    }
}

// ---------------------------------------------------------------------------
// z[n][d] = sum_p beta[p] * emb[p][n][d]   (emb bf16, out fp32)
// ---------------------------------------------------------------------------
__global__ __launch_bounds__(256) void combine(const ushort* __restrict__ emb,
                                               const float* __restrict__ beta,
                                               float* __restrict__ out)
{
    const float b0 = beta[0], b1 = beta[1], b2 = beta[2];
    const size_t tot = (size_t)N_NODES * 64;
    size_t i = ((size_t)blockIdx.x * 256 + threadIdx.x) * 8;
    if (i < tot) {
        uint4 e0 = *(const uint4*)&emb[i];
        uint4 e1 = *(const uint4*)&emb[tot + i];
        uint4 e2 = *(const uint4*)&emb[2 * tot + i];
        float o[8];
        o[0] = b0*bfl(e0.x) + b1*bfl(e1.x) + b2*bfl(e2.x);
        o[1] = b0*bfh(e0.x) + b1*bfh(e1.x) + b2*bfh(e2.x);
        o[2] = b0*bfl(e0.y) + b1*bfl(e1.y) + b2*bfl(e2.y);
        o[3] = b0*bfh(e0.y) + b1*bfh(e1.y) + b2*bfh(e2.y);
        o[4] = b0*bfl(e0.z) + b1*bfl(e1.z) + b2*bfl(e2.z);
        o[5] = b0*bfh(e0.z) + b1*bfh(e1.z) + b2*bfh(e2.z);
        o[6] = b0*bfl(e0.w) + b1*bfl(e1.w) + b2*bfl(e2.w);
        o[7] = b0*bfh(e0.w) + b1*bfh(e1.w) + b2*bfh(e2.w);
        *(float4*)&out[i]     = make_float4(o[0], o[1], o[2], o[3]);
        *(float4*)&out[i + 4] = make_float4(o[4], o[5], o[6], o[7]);
    }
}

// ---------------------------------------------------------------------------
extern "C" void kernel_launch(void* const* d_in, const int* in_sizes, int n_in,
                              void* d_out, int out_size, void* d_ws, size_t ws_size,
                              hipStream_t stream)
{
    const float* feats = (const float*)d_in[0];
    const int*   rows  = (const int*)  d_in[1];
    const int*   cols  = (const int*)  d_in[2];
    const float* vals  = (const float*)d_in[3];
    const float* W0    = (const float*)d_in[4];
    const float* b0    = (const float*)d_in[5];
    const float* Wg    = (const float*)d_in[6];
    const float* bg    = (const float*)d_in[7];
    const float* alpha = (const float*)d_in[8];
    const float* Wa    = (const float*)d_in[9];
    const float* ba    = (const float*)d_in[10];
    const float* att   = (const float*)d_in[11];
    float* out = (float*)d_out;

    const size_t ND = (size_t)N_NODES * 64;      // 3.2M elements
    char* base = (char*)d_ws;
    ushort* emb    = (ushort*)base;              base += 3 * ND * 2;        // 19.2 MB
    ushort* s_all  = (ushort*)base;              base += 3 * ND * 2;        // 19.2 MB ([p][n][64])
    ushort* W0h    = (ushort*)base;              base += 64 * 1024 * 2;
    ushort* Wgh    = (ushort*)base;              base += PP * 64 * 64 * 2;
    ushort* Wah    = (ushort*)base;              base += 64 * 64 * 2;
    int*    pcur3  = (int*)base;                 base += PP * NPC * 4;
    float*  sp     = (float*)base;               base += 192 * 4;
    float*  beta   = (float*)base;               base += 64 * 4;
    int*    rowbeg3 = (int*)base;                base += PP * N_NODES * 4;  // 600 KB
    int*    rowend3 = (int*)base;                base += PP * N_NODES * 4;  // 600 KB
    base = (char*)(((size_t)base + 255) & ~(size_t)255);
    float*  hpart  = (float*)base;               base += (size_t)4 * NB1 * 8192 * 4;  // 51.2 MB
    uint2*  coarsebuf = (uint2*)base;            base += (size_t)PP * NPC * CCAP * 8; // 41.5 MB
    uint*   sortpk    = (uint*)base;             base += (size_t)PP * NPC * CCAP * 4; // 20.8 MB

    // zero pcur3 + sp (contiguous)
    hipMemsetAsync(pcur3, 0, (PP * NPC + 192) * sizeof(int), stream);

    split_weights<<<(64 * 1024 + PP * 64 * 64 + 64 * 64 + 255) / 256, 256, 0, stream>>>(
        W0, Wg, Wa, W0h, Wgh, Wah);

    // fused: gemm1 split-K(x4) + part1 edge binning, role-interleaved
    fused_front<<<GEMM1B + PART1B, 512, 0, stream>>>(
        feats, W0h, hpart, rows, cols, vals, pcur3, coarsebuf);

    // fused: gemm2_combine + sort2, overlapped
    fused_mid<<<NB1 + 3 * NPC, 512, 0, stream>>>(
        hpart, b0, Wgh, s_all, coarsebuf, pcur3, sortpk, rowbeg3, rowend3);

    spmm_gather<<<3 * 12500, 256, 0, stream>>>(
        sortpk, rowbeg3, rowend3, s_all, bg, alpha, emb);

    postproc<<<3 * 782, 256, 0, stream>>>(emb, Wah, ba, sp);
    beta_kernel<<<1, 64, 0, stream>>>(sp, att, beta);
    combine<<<(int)((ND / 8 + 255) / 256), 256, 0, stream>>>(emb, beta, out);
}